// Round 4
// baseline (675.286 us; speedup 1.0000x reference)
//
#include <hip/hip_runtime.h>
#include <hip/hip_fp16.h>

// out = clip(hq - L(hq - lq), -1, 1),  L = B16.B8.B4.B2.B1 (dilated 3x3 binomial, replicate pad)
// Fully fused: one kernel, 5 levels on an LDS-resident fp16 tile, PACKED fp16 arithmetic.
// Tile: 120x128 output, halo 32 -> region 184x192 (stride 200 halves, 74 KB -> 2 blocks/CU).
// In-place single-phase passes, register staging (<=9 int4, fits 128-VGPR budget at 4 waves/EU).

static constexpr int IMG_H = 720;
static constexpr int IMG_W = 1280;
static constexpr int TH = 120, TW = 128;
static constexpr int TX_N = 10, TY_N = 6, NPL = 48;
static constexpr int STRIDE = 200;                 // halves per LDS row
static constexpr int BUF_HALVES = 185 * STRIDE;    // 74,000 B

union U4 { int4 i4; unsigned u[4]; __half2 h[4]; };

__device__ __forceinline__ float4 ld4(const float* p) {
    return *reinterpret_cast<const float4*>(p);
}
__device__ __forceinline__ void st4(float* p, const float4& v) {
    *reinterpret_cast<float4*>(p) = v;
}
__device__ __forceinline__ int4 pack8h(const float* v) {
    union { __half2 h2[4]; int4 i4; } u;
#pragma unroll
    for (int i = 0; i < 4; ++i)
        u.h2[i] = __floats2half2_rn(v[2 * i], v[2 * i + 1]);
    return u.i4;
}

// One in-place blur pass (single phase): read+compute into regs, barrier, write, barrier.
// o = fma(center, 0.5, 0.25*(left+right)) in packed fp16.
template<int R, int RLO, int RHI, int B0, int NC, bool VERT>
__device__ void pass(__half* buf, int tid, int XLO, int XHI, int YLO, int YHI, bool edgex) {
    constexpr int NCH   = (RHI - RLO + 1) * NC;
    constexpr int ITERS = (NCH + 511) / 512;
    const __half2 Q = __floats2half2_rn(0.25f, 0.25f);
    const __half2 H = __floats2half2_rn(0.5f, 0.5f);
    int4 stage[ITERS];
#pragma unroll
    for (int k = 0; k < ITERS; ++k) {
        int idx = tid + k * 512;
        if (idx < NCH) {
            int lr  = RLO + idx / NC;
            int lc0 = B0 + (idx % NC) * 8;
            __half* row = buf + lr * STRIDE;
            U4 o;
            if constexpr (VERT) {
                int lrm = lr - R; if (lrm < YLO) lrm = YLO;
                int lrp = lr + R; if (lrp > YHI) lrp = YHI;
                U4 a, b, c;
                a.i4 = *reinterpret_cast<const int4*>(buf + lrm * STRIDE + lc0);
                b.i4 = *reinterpret_cast<const int4*>(row + lc0);
                c.i4 = *reinterpret_cast<const int4*>(buf + lrp * STRIDE + lc0);
#pragma unroll
                for (int i = 0; i < 4; ++i)
                    o.h[i] = __hfma2(b.h[i], H, __hmul2(__hadd2(a.h[i], c.h[i]), Q));
            } else {
                bool clampx = edgex && (lc0 - R < XLO || lc0 + 7 + R > XHI);
                if (!clampx) {
                    U4 b, l, r;
                    b.i4 = *reinterpret_cast<const int4*>(row + lc0);
                    if constexpr (R == 16) {
                        l.i4 = *reinterpret_cast<const int4*>(row + lc0 - 16);
                        r.i4 = *reinterpret_cast<const int4*>(row + lc0 + 16);
                    } else {
                        U4 A, C;
                        A.i4 = *reinterpret_cast<const int4*>(row + lc0 - 8);
                        C.i4 = *reinterpret_cast<const int4*>(row + lc0 + 8);
                        unsigned w[12];
#pragma unroll
                        for (int i = 0; i < 4; ++i) {
                            w[i] = A.u[i]; w[4 + i] = b.u[i]; w[8 + i] = C.u[i];
                        }
#pragma unroll
                        for (int i = 0; i < 4; ++i) {
                            if constexpr (R == 1) {
                                l.u[i] = (w[3 + i] >> 16) | (w[4 + i] << 16);
                                r.u[i] = (w[4 + i] >> 16) | (w[5 + i] << 16);
                            } else if constexpr (R == 2) {
                                l.u[i] = w[3 + i]; r.u[i] = w[5 + i];
                            } else if constexpr (R == 4) {
                                l.u[i] = w[2 + i]; r.u[i] = w[6 + i];
                            } else { // R == 8
                                l.u[i] = w[i];     r.u[i] = w[8 + i];
                            }
                        }
                    }
#pragma unroll
                    for (int i = 0; i < 4; ++i)
                        o.h[i] = __hfma2(b.h[i], H, __hmul2(__hadd2(l.h[i], r.h[i]), Q));
                } else {
                    // per-element x-clamped (tx-edge blocks only, few chunks)
                    float ov[8];
#pragma unroll
                    for (int j = 0; j < 8; ++j) {
                        int lc = lc0 + j;
                        int ml = lc - R; if (ml < XLO) ml = XLO;
                        int mr = lc + R; if (mr > XHI) mr = XHI;
                        float a = __half2float(buf[lr * STRIDE + ml]);
                        float b = __half2float(buf[lr * STRIDE + lc]);
                        float c = __half2float(buf[lr * STRIDE + mr]);
                        ov[j] = 0.25f * (a + c) + 0.5f * b;
                    }
                    o.i4 = pack8h(ov);
                }
            }
            stage[k] = o.i4;
        }
    }
    __syncthreads();
#pragma unroll
    for (int k = 0; k < ITERS; ++k) {
        int idx = tid + k * 512;
        if (idx < NCH) {
            int lr  = RLO + idx / NC;
            int lc0 = B0 + (idx % NC) * 8;
            *reinterpret_cast<int4*>(buf + lr * STRIDE + lc0) = stage[k];
        }
    }
    __syncthreads();
}

__global__ __launch_bounds__(512)
__attribute__((amdgpu_waves_per_eu(4, 4)))   // LDS caps at 2 blocks/CU; allow 128 VGPRs
void wavelet_fused_kernel(
        const float* __restrict__ hq, const float* __restrict__ lq,
        float* __restrict__ out) {
    __shared__ __align__(16) __half buf[BUF_HALVES];

    // XCD-aware swizzle (2880 % 8 == 0 -> simple bijective form)
    const int nwg = NPL * TY_N * TX_N;      // 2880
    const int cpx = nwg / 8;                // 360
    int bid = blockIdx.x;
    int swz = (bid % 8) * cpx + bid / 8;
    const int tx = swz % TX_N;
    const int ty = (swz / TX_N) % TY_N;
    const int p  = swz / (TX_N * TY_N);

    const int tid = threadIdx.x;
    const size_t plane = (size_t)p * (size_t)(IMG_H * IMG_W);
    const float* hp = hq + plane;
    const float* lp = lq + plane;
    float* op = out + plane;

    const int Y0 = ty * TH, X0 = tx * TW;
    const int RY0 = Y0 - 32, RX0 = X0 - 32;
    const bool edgex = (tx == 0) || (tx == TX_N - 1);
    const int XLO = (tx == 0)        ?  32 : -100000;   // lc of image x=0
    const int XHI = (tx == TX_N - 1) ? 159 :  100000;   // lc of image x=1279
    const int YLO = (ty == 0)        ?  32 : -100000;   // lr of image y=0
    const int YHI = (ty == TY_N - 1) ? 151 :  100000;   // lr of image y=719

    // ---- load phase: d = hq - lq into fp16 region (184 rows x 24 chunks) ----
#pragma unroll
    for (int k = 0; k < 9; ++k) {
        int idx = tid + k * 512;
        if (idx < 184 * 24) {
            int lr  = idx / 24;
            int lc0 = (idx % 24) * 8;
            int gy = RY0 + lr; gy = gy < 0 ? 0 : (gy > IMG_H - 1 ? IMG_H - 1 : gy);
            int gx0 = RX0 + lc0;
            const float* hrow = hp + (size_t)gy * IMG_W;
            const float* lrow = lp + (size_t)gy * IMG_W;
            float v[8];
            if (gx0 >= 0 && gx0 + 7 <= IMG_W - 1) {
                float4 a0 = ld4(hrow + gx0), a1 = ld4(hrow + gx0 + 4);
                float4 b0 = ld4(lrow + gx0), b1 = ld4(lrow + gx0 + 4);
                v[0] = a0.x - b0.x; v[1] = a0.y - b0.y; v[2] = a0.z - b0.z; v[3] = a0.w - b0.w;
                v[4] = a1.x - b1.x; v[5] = a1.y - b1.y; v[6] = a1.z - b1.z; v[7] = a1.w - b1.w;
            } else {
#pragma unroll
                for (int j = 0; j < 8; ++j) {
                    int gx = gx0 + j; gx = gx < 0 ? 0 : (gx > IMG_W - 1 ? IMG_W - 1 : gx);
                    v[j] = hrow[gx] - lrow[gx];
                }
            }
            *reinterpret_cast<int4*>(buf + lr * STRIDE + lc0) = pack8h(v);
        }
    }
    __syncthreads();

    // ---- 9 in-place passes ----
    pass< 1,  1, 182,  0, 24, false>(buf, tid, XLO, XHI, YLO, YHI, edgex);  // H1
    pass< 1,  2, 181,  0, 24, true >(buf, tid, XLO, XHI, YLO, YHI, edgex);  // V1
    pass< 2,  2, 181,  0, 24, false>(buf, tid, XLO, XHI, YLO, YHI, edgex);  // H2
    pass< 2,  4, 179,  0, 24, true >(buf, tid, XLO, XHI, YLO, YHI, edgex);  // V2
    pass< 4,  4, 179,  8, 22, false>(buf, tid, XLO, XHI, YLO, YHI, edgex);  // H3
    pass< 4,  8, 175,  8, 22, true >(buf, tid, XLO, XHI, YLO, YHI, edgex);  // V3
    pass< 8,  8, 175, 16, 20, false>(buf, tid, XLO, XHI, YLO, YHI, edgex);  // H4
    pass< 8, 16, 167, 16, 20, true >(buf, tid, XLO, XHI, YLO, YHI, edgex);  // V4
    pass<16, 16, 167, 32, 16, false>(buf, tid, XLO, XHI, YLO, YHI, edgex);  // H5

    // ---- V5 (R=16) fused with clip + store: rows lr 32..151, cols lc0 = 32+8c ----
    const __half2 Q = __floats2half2_rn(0.25f, 0.25f);
    const __half2 Hh = __floats2half2_rn(0.5f, 0.5f);
#pragma unroll
    for (int k = 0; k < 4; ++k) {
        int idx = tid + k * 512;
        if (idx < 120 * 16) {
            int r = idx / 16, c = idx % 16;
            int lr = 32 + r, lc0 = 32 + c * 8;
            int lrm = lr - 16; if (lrm < YLO) lrm = YLO;
            int lrp = lr + 16; if (lrp > YHI) lrp = YHI;
            U4 a, b, cc, t;
            a.i4  = *reinterpret_cast<const int4*>(buf + lrm * STRIDE + lc0);
            b.i4  = *reinterpret_cast<const int4*>(buf + lr  * STRIDE + lc0);
            cc.i4 = *reinterpret_cast<const int4*>(buf + lrp * STRIDE + lc0);
#pragma unroll
            for (int i = 0; i < 4; ++i)
                t.h[i] = __hfma2(b.h[i], Hh, __hmul2(__hadd2(a.h[i], cc.h[i]), Q));
            int gy = Y0 + r, gx0 = X0 + c * 8;
            const float* hrow = hp + (size_t)gy * IMG_W + gx0;
            float4 q0 = ld4(hrow), q1 = ld4(hrow + 4);
            float q[8] = {q0.x, q0.y, q0.z, q0.w, q1.x, q1.y, q1.z, q1.w};
            float o[8];
#pragma unroll
            for (int i = 0; i < 4; ++i) {
                float2 f = __half22float2(t.h[i]);
                o[2 * i]     = fminf(fmaxf(q[2 * i]     - f.x, -1.f), 1.f);
                o[2 * i + 1] = fminf(fmaxf(q[2 * i + 1] - f.y, -1.f), 1.f);
            }
            float* orow = op + (size_t)gy * IMG_W + gx0;
            st4(orow,     make_float4(o[0], o[1], o[2], o[3]));
            st4(orow + 4, make_float4(o[4], o[5], o[6], o[7]));
        }
    }
}

extern "C" void kernel_launch(void* const* d_in, const int* in_sizes, int n_in,
                              void* d_out, int out_size, void* d_ws, size_t ws_size,
                              hipStream_t stream) {
    const float* hq = (const float*)d_in[0];
    const float* lq = (const float*)d_in[1];
    float* out = (float*)d_out;

    wavelet_fused_kernel<<<dim3(NPL * TY_N * TX_N), dim3(512), 0, stream>>>(hq, lq, out);
}

// Round 5
// 532.884 us; speedup vs baseline: 1.2672x; 1.2672x over previous
//
#include <hip/hip_runtime.h>
#include <hip/hip_fp16.h>

// out = clip(hq - L(hq - lq), -1, 1),  L = B16.B8.B4.B2.B1 (dilated 3x3 binomial, replicate pad)
// Fully fused: one kernel, 5 levels on an LDS-resident fp16 tile, PACKED fp16 arithmetic.
// Tile: 120x128 output, halo 32 -> region 184x192 (stride 200 halves, 74 KB -> 2 blocks/CU).
// In-place passes, phase-split along the hazard-free axis (rows for H, cols for V) so
// register staging stays <= 4 int4 (proven no-spill at 64-VGPR budget). Barriers merged:
// write_p || compute_{p+1} touch disjoint LDS -> NPH+1 barriers per pass instead of 2*NPH.

static constexpr int IMG_H = 720;
static constexpr int IMG_W = 1280;
static constexpr int TH = 120, TW = 128;
static constexpr int TX_N = 10, TY_N = 6, NPL = 48;
static constexpr int STRIDE = 200;                 // halves per LDS row
static constexpr int BUF_HALVES = 185 * STRIDE;    // 74,000 B

union U4 { int4 i4; unsigned u[4]; __half2 h[4]; };

__device__ __forceinline__ float4 ld4(const float* p) {
    return *reinterpret_cast<const float4*>(p);
}
__device__ __forceinline__ void st4(float* p, const float4& v) {
    *reinterpret_cast<float4*>(p) = v;
}
__device__ __forceinline__ int4 pack8h(const float* v) {
    union { __half2 h2[4]; int4 i4; } u;
#pragma unroll
    for (int i = 0; i < 4; ++i)
        u.h2[i] = __floats2half2_rn(v[2 * i], v[2 * i + 1]);
    return u.i4;
}

// One in-place blur pass. o = fma(center, 0.5, 0.25*(left+right)) in packed fp16.
// H (VERT=false): phases partition ROWS; V (VERT=true): phases partition COL-CHUNKS.
// Addressing: (r_t, c_t) fixed per thread; rows walk by RPB per k-step.
template<int R, int RLO, int RHI, int B0, int NC, bool VERT, int NPH>
__device__ void pass(__half* buf, int tid, int XLO, int XHI, int YLO, int YHI, bool edgex) {
    constexpr int NR = RHI - RLO + 1;
    const __half2 Qh = __floats2half2_rn(0.25f, 0.25f);
    const __half2 Hh = __floats2half2_rn(0.5f, 0.5f);
    if constexpr (!VERT) {
        constexpr int RPP   = (NR + NPH - 1) / NPH;   // rows per phase
        constexpr int RPB   = 512 / NC;               // rows per k-step
        constexpr int ITERS = (RPP + RPB - 1) / RPB;
        const int r_t = tid / NC;
        const int lc0 = B0 + (tid % NC) * 8;
        const bool lane_ok = (r_t < RPB);
        const bool clampx = edgex && (lc0 - R < XLO || lc0 + 7 + R > XHI);
        int4 stage[ITERS];
#pragma unroll
        for (int ph = 0; ph < NPH; ++ph) {
            const int r0   = RLO + ph * RPP;
            const int nrow = (NR - ph * RPP) < RPP ? (NR - ph * RPP) : RPP;
#pragma unroll
            for (int k = 0; k < ITERS; ++k) {
                int rr = r_t + k * RPB;
                if (lane_ok && rr < nrow) {
                    __half* row = buf + (r0 + rr) * STRIDE;
                    U4 o;
                    if (!clampx) {
                        U4 b, l, r;
                        b.i4 = *reinterpret_cast<const int4*>(row + lc0);
                        if constexpr (R == 16) {
                            l.i4 = *reinterpret_cast<const int4*>(row + lc0 - 16);
                            r.i4 = *reinterpret_cast<const int4*>(row + lc0 + 16);
                        } else {
                            U4 A, C;
                            A.i4 = *reinterpret_cast<const int4*>(row + lc0 - 8);
                            C.i4 = *reinterpret_cast<const int4*>(row + lc0 + 8);
                            unsigned w[12];
#pragma unroll
                            for (int i = 0; i < 4; ++i) {
                                w[i] = A.u[i]; w[4 + i] = b.u[i]; w[8 + i] = C.u[i];
                            }
#pragma unroll
                            for (int i = 0; i < 4; ++i) {
                                if constexpr (R == 1) {
                                    l.u[i] = (w[3 + i] >> 16) | (w[4 + i] << 16);
                                    r.u[i] = (w[4 + i] >> 16) | (w[5 + i] << 16);
                                } else if constexpr (R == 2) {
                                    l.u[i] = w[3 + i]; r.u[i] = w[5 + i];
                                } else if constexpr (R == 4) {
                                    l.u[i] = w[2 + i]; r.u[i] = w[6 + i];
                                } else { // R == 8
                                    l.u[i] = w[i];     r.u[i] = w[8 + i];
                                }
                            }
                        }
#pragma unroll
                        for (int i = 0; i < 4; ++i)
                            o.h[i] = __hfma2(b.h[i], Hh, __hmul2(__hadd2(l.h[i], r.h[i]), Qh));
                    } else {
                        // per-element x-clamped (tx-edge blocks only, few chunks)
                        float ov[8];
#pragma unroll
                        for (int j = 0; j < 8; ++j) {
                            int lc = lc0 + j;
                            int ml = lc - R; if (ml < XLO) ml = XLO;
                            int mr = lc + R; if (mr > XHI) mr = XHI;
                            float a = __half2float(row[ml]);
                            float b = __half2float(row[lc]);
                            float c = __half2float(row[mr]);
                            ov[j] = 0.25f * (a + c) + 0.5f * b;
                        }
                        o.i4 = pack8h(ov);
                    }
                    stage[k] = o.i4;
                }
            }
            __syncthreads();
#pragma unroll
            for (int k = 0; k < ITERS; ++k) {
                int rr = r_t + k * RPB;
                if (lane_ok && rr < nrow)
                    *reinterpret_cast<int4*>(buf + (r0 + rr) * STRIDE + lc0) = stage[k];
            }
            // no barrier here: next phase's compute reads disjoint rows
        }
        __syncthreads();
    } else {
        constexpr int CPP   = NC / NPH;               // col-chunks per phase (exact)
        constexpr int RPB   = 512 / CPP;              // rows per k-step
        constexpr int ITERS = (NR + RPB - 1) / RPB;
        const int r_t = tid / CPP;
        const int c_t = tid % CPP;
        const bool lane_ok = (r_t < RPB);
        int4 stage[ITERS];
#pragma unroll
        for (int ph = 0; ph < NPH; ++ph) {
            const int lc0 = B0 + (ph * CPP + c_t) * 8;
#pragma unroll
            for (int k = 0; k < ITERS; ++k) {
                int rr = r_t + k * RPB;
                if (lane_ok && rr < NR) {
                    int lr = RLO + rr;
                    int lrm = lr - R; if (lrm < YLO) lrm = YLO;
                    int lrp = lr + R; if (lrp > YHI) lrp = YHI;
                    U4 a, b, c, o;
                    a.i4 = *reinterpret_cast<const int4*>(buf + lrm * STRIDE + lc0);
                    b.i4 = *reinterpret_cast<const int4*>(buf + lr  * STRIDE + lc0);
                    c.i4 = *reinterpret_cast<const int4*>(buf + lrp * STRIDE + lc0);
#pragma unroll
                    for (int i = 0; i < 4; ++i)
                        o.h[i] = __hfma2(b.h[i], Hh, __hmul2(__hadd2(a.h[i], c.h[i]), Qh));
                    stage[k] = o.i4;
                }
            }
            __syncthreads();
#pragma unroll
            for (int k = 0; k < ITERS; ++k) {
                int rr = r_t + k * RPB;
                if (lane_ok && rr < NR)
                    *reinterpret_cast<int4*>(buf + (RLO + rr) * STRIDE + lc0) = stage[k];
            }
            // no barrier here: next phase's compute reads disjoint columns
        }
        __syncthreads();
    }
}

__global__ __launch_bounds__(512)
__attribute__((amdgpu_waves_per_eu(4, 4)))
void wavelet_fused_kernel(
        const float* __restrict__ hq, const float* __restrict__ lq,
        float* __restrict__ out) {
    __shared__ __align__(16) __half buf[BUF_HALVES];

    // XCD-aware swizzle (2880 % 8 == 0 -> simple bijective form)
    const int nwg = NPL * TY_N * TX_N;      // 2880
    const int cpx = nwg / 8;                // 360
    int bid = blockIdx.x;
    int swz = (bid % 8) * cpx + bid / 8;
    const int tx = swz % TX_N;
    const int ty = (swz / TX_N) % TY_N;
    const int p  = swz / (TX_N * TY_N);

    const int tid = threadIdx.x;
    const size_t plane = (size_t)p * (size_t)(IMG_H * IMG_W);
    const float* hp = hq + plane;
    const float* lp = lq + plane;
    float* op = out + plane;

    const int Y0 = ty * TH, X0 = tx * TW;
    const int RY0 = Y0 - 32, RX0 = X0 - 32;
    const bool edgex = (tx == 0) || (tx == TX_N - 1);
    const int XLO = (tx == 0)        ?  32 : -100000;   // lc of image x=0
    const int XHI = (tx == TX_N - 1) ? 159 :  100000;   // lc of image x=1279
    const int YLO = (ty == 0)        ?  32 : -100000;   // lr of image y=0
    const int YHI = (ty == TY_N - 1) ? 151 :  100000;   // lr of image y=719

    // ---- load phase: d = hq - lq into fp16 region (184 rows x 24 chunks) ----
    {
        const int r_t = tid / 24;
        const int c_t = tid % 24;
        const bool lane_ok = (r_t < 21);            // 504 active threads, 21 rows per k
        const int lc0 = c_t * 8;
        const int gx0 = RX0 + lc0;
        const bool xin = (gx0 >= 0 && gx0 + 7 <= IMG_W - 1);
#pragma unroll
        for (int k = 0; k < 9; ++k) {
            int rr = r_t + k * 21;
            if (lane_ok && rr < 184) {
                int gy = RY0 + rr; gy = gy < 0 ? 0 : (gy > IMG_H - 1 ? IMG_H - 1 : gy);
                const float* hrow = hp + (size_t)gy * IMG_W;
                const float* lrow = lp + (size_t)gy * IMG_W;
                float v[8];
                if (xin) {
                    float4 a0 = ld4(hrow + gx0), a1 = ld4(hrow + gx0 + 4);
                    float4 b0 = ld4(lrow + gx0), b1 = ld4(lrow + gx0 + 4);
                    v[0] = a0.x - b0.x; v[1] = a0.y - b0.y; v[2] = a0.z - b0.z; v[3] = a0.w - b0.w;
                    v[4] = a1.x - b1.x; v[5] = a1.y - b1.y; v[6] = a1.z - b1.z; v[7] = a1.w - b1.w;
                } else {
#pragma unroll
                    for (int j = 0; j < 8; ++j) {
                        int gx = gx0 + j; gx = gx < 0 ? 0 : (gx > IMG_W - 1 ? IMG_W - 1 : gx);
                        v[j] = hrow[gx] - lrow[gx];
                    }
                }
                *reinterpret_cast<int4*>(buf + rr * STRIDE + lc0) = pack8h(v);
            }
        }
    }
    __syncthreads();

    // ---- 9 in-place passes ----
    pass< 1,  1, 182,  0, 24, false, 3>(buf, tid, XLO, XHI, YLO, YHI, edgex);  // H1
    pass< 1,  2, 181,  0, 24, true , 3>(buf, tid, XLO, XHI, YLO, YHI, edgex);  // V1
    pass< 2,  2, 181,  0, 24, false, 3>(buf, tid, XLO, XHI, YLO, YHI, edgex);  // H2
    pass< 2,  4, 179,  0, 24, true , 3>(buf, tid, XLO, XHI, YLO, YHI, edgex);  // V2
    pass< 4,  4, 179,  8, 22, false, 2>(buf, tid, XLO, XHI, YLO, YHI, edgex);  // H3
    pass< 4,  8, 175,  8, 22, true , 2>(buf, tid, XLO, XHI, YLO, YHI, edgex);  // V3
    pass< 8,  8, 175, 16, 20, false, 2>(buf, tid, XLO, XHI, YLO, YHI, edgex);  // H4
    pass< 8, 16, 167, 16, 20, true , 2>(buf, tid, XLO, XHI, YLO, YHI, edgex);  // V4
    pass<16, 16, 167, 32, 16, false, 2>(buf, tid, XLO, XHI, YLO, YHI, edgex);  // H5

    // ---- V5 (R=16) fused with clip + store: rows lr 32..151, cols lc0 = 32+8c ----
    {
        const __half2 Qh = __floats2half2_rn(0.25f, 0.25f);
        const __half2 Hh = __floats2half2_rn(0.5f, 0.5f);
        const int r_t = tid / 16;        // 32 rows per k-step, all 512 threads active
        const int c_t = tid % 16;
        const int lc0 = 32 + c_t * 8;
#pragma unroll
        for (int k = 0; k < 4; ++k) {
            int rr = r_t + k * 32;
            if (rr < 120) {
                int lr = 32 + rr;
                int lrm = lr - 16; if (lrm < YLO) lrm = YLO;
                int lrp = lr + 16; if (lrp > YHI) lrp = YHI;
                U4 a, b, cc, t;
                a.i4  = *reinterpret_cast<const int4*>(buf + lrm * STRIDE + lc0);
                b.i4  = *reinterpret_cast<const int4*>(buf + lr  * STRIDE + lc0);
                cc.i4 = *reinterpret_cast<const int4*>(buf + lrp * STRIDE + lc0);
#pragma unroll
                for (int i = 0; i < 4; ++i)
                    t.h[i] = __hfma2(b.h[i], Hh, __hmul2(__hadd2(a.h[i], cc.h[i]), Qh));
                int gy = Y0 + rr, gx0 = X0 + c_t * 8;
                const float* hrow = hp + (size_t)gy * IMG_W + gx0;
                float4 q0 = ld4(hrow), q1 = ld4(hrow + 4);
                float q[8] = {q0.x, q0.y, q0.z, q0.w, q1.x, q1.y, q1.z, q1.w};
                float o[8];
#pragma unroll
                for (int i = 0; i < 4; ++i) {
                    float2 f = __half22float2(t.h[i]);
                    o[2 * i]     = fminf(fmaxf(q[2 * i]     - f.x, -1.f), 1.f);
                    o[2 * i + 1] = fminf(fmaxf(q[2 * i + 1] - f.y, -1.f), 1.f);
                }
                float* orow = op + (size_t)gy * IMG_W + gx0;
                st4(orow,     make_float4(o[0], o[1], o[2], o[3]));
                st4(orow + 4, make_float4(o[4], o[5], o[6], o[7]));
            }
        }
    }
}

extern "C" void kernel_launch(void* const* d_in, const int* in_sizes, int n_in,
                              void* d_out, int out_size, void* d_ws, size_t ws_size,
                              hipStream_t stream) {
    const float* hq = (const float*)d_in[0];
    const float* lq = (const float*)d_in[1];
    float* out = (float*)d_out;

    wavelet_fused_kernel<<<dim3(NPL * TY_N * TX_N), dim3(512), 0, stream>>>(hq, lq, out);
}